// Round 8
// baseline (762.542 us; speedup 1.0000x reference)
//
#include <hip/hip_runtime.h>

#define N_NODES 50000
#define N_EDGES 800000
#define IN_CH   128
#define HID_CH  512
#define OUT_CH  256

// 128-node dst-buckets; one block accumulates a bucket in 64 KB LDS.
#define BKT_SHIFT 7
#define BKT_NODES 128
#define NBKT ((N_NODES + BKT_NODES - 1) / BKT_NODES)        // 391
#define BCAP 4096                                           // mean 2046, 2x headroom
#define P1_EPT    8
#define P1_EPB    (512 * P1_EPT)                            // 4096 edges/block
#define P1_BLOCKS ((N_EDGES + P1_EPB - 1) / P1_EPB)         // 196

typedef __attribute__((ext_vector_type(8))) short bf16x8;
typedef __attribute__((ext_vector_type(4))) float f32x4;

static __device__ __forceinline__ ushort f2bf(float f) {
    uint u = __float_as_uint(f);
    uint r = u + 0x7fffu + ((u >> 16) & 1u);   // RNE; inputs are finite
    return (ushort)(r >> 16);
}

// ---------------------------------------------------------------------------
// W12t[j][i] = sum_k W1[i][k]*W2[k][j]  (bf16, TRANSPOSED: [256][128])
// b2[j]     = sum_k b1[k]*W2[k][j]     (f32)
// ---------------------------------------------------------------------------
__global__ void build_w12(const float* __restrict__ W1,
                          const float* __restrict__ b1,
                          const float* __restrict__ W2,
                          ushort* __restrict__ W12t,
                          float* __restrict__ b2) {
    const int i = blockIdx.x;        // 0..128 (128 == bias row)
    const int j = threadIdx.x;       // 0..255
    const float* arow = (i < IN_CH) ? (W1 + (size_t)i * HID_CH) : b1;
    float acc = 0.f;
#pragma unroll 8
    for (int k = 0; k < HID_CH; ++k)
        acc = fmaf(arow[k], W2[(size_t)k * OUT_CH + j], acc);
    if (i < IN_CH) W12t[(size_t)j * IN_CH + i] = f2bf(acc);
    else           b2[j] = acc;
}

// ---------------------------------------------------------------------------
// x (f32) -> xw (bf16, SPLIT layout): word w of node n = (ch w | ch w+64).
// Only bucket_accum reads xw, so the permuted layout is private.
// Also zeroes bucketcnt (runs before partition_edges on the stream).
// ---------------------------------------------------------------------------
__global__ void cvt_bf16(const float* __restrict__ x, uint* __restrict__ xw,
                         int* __restrict__ bucketcnt) {
    const int gid = blockIdx.x * 256 + threadIdx.x;
    if (gid < NBKT) bucketcnt[gid] = 0;
    if (gid >= N_NODES * 64) return;
    const int n = gid >> 6, w = gid & 63;
    const float lo = x[(size_t)n * IN_CH + w];
    const float hi = x[(size_t)n * IN_CH + w + 64];
    xw[gid] = ((uint)f2bf(hi) << 16) | (uint)f2bf(lo);
}

// ---------------------------------------------------------------------------
// Partition edges into 391 fixed-capacity dst-buckets (128 nodes each).
// Packed word: b<<23 | src<<7 | (dst&127). LDS-staged, bucket-contiguous
// coalesced writes; per-bucket base = b*BCAP + atomic count.
// ---------------------------------------------------------------------------
__global__ __launch_bounds__(512) void partition_edges(const int* __restrict__ ei,
                                                       int* __restrict__ bucketcnt,
                                                       uint* __restrict__ pairbuf) {
    __shared__ uint stage[P1_EPB];                 // 16 KB
    __shared__ int cnt[512], off[512], cur[512], base[512];
    const int t = threadIdx.x;
    const int e0 = blockIdx.x * P1_EPB;

    cnt[t] = 0;
    __syncthreads();

    uint pk[P1_EPT];
    int  bk[P1_EPT];
    bool vl[P1_EPT];
#pragma unroll
    for (int i = 0; i < P1_EPT; ++i) {
        const int e = e0 + i * 512 + t;
        vl[i] = (e < N_EDGES);
        if (vl[i]) {
            const int src = ei[e];
            const int dst = ei[N_EDGES + e];
            const int b = dst >> BKT_SHIFT;
            bk[i] = b;
            pk[i] = ((uint)b << 23) | ((uint)src << 7) | (uint)(dst & (BKT_NODES - 1));
            atomicAdd(&cnt[b], 1);
        }
    }
    __syncthreads();

    // exclusive scan of cnt[0..511] -> off
    off[t] = cnt[t];
    __syncthreads();
#pragma unroll
    for (int d = 1; d < 512; d <<= 1) {
        const int u = (t >= d) ? off[t - d] : 0;
        __syncthreads();
        off[t] += u;
        __syncthreads();
    }
    off[t] -= cnt[t];                              // exclusive
    cur[t] = off[t];
    if (t < NBKT && cnt[t] > 0)
        base[t] = t * BCAP + atomicAdd(&bucketcnt[t], cnt[t]);
    __syncthreads();

#pragma unroll
    for (int i = 0; i < P1_EPT; ++i)
        if (vl[i]) {
            const int lp = atomicAdd(&cur[bk[i]], 1);
            stage[lp] = pk[i];
        }
    __syncthreads();

    const int TOT = off[511] + cnt[511];
    for (int idx = t; idx < TOT; idx += 512) {
        const uint p = stage[idx];
        const int b = (int)(p >> 23);
        pairbuf[base[b] + (idx - off[b])] = p;
    }
}

// ---------------------------------------------------------------------------
// Per-bucket accumulate: LDS f32 agg[128][128] (64 KB -> 2 blocks/CU).
// Init with self rows (residual), then ds_add_f32 per edge; write bf16 aggw.
// Lane l owns channels (l, l+64): LDS bank = l&31 -> 2 lanes/bank (free).
// ---------------------------------------------------------------------------
__global__ __launch_bounds__(512) void bucket_accum(const uint* __restrict__ xw,
                                                    const int* __restrict__ bucketcnt,
                                                    const uint* __restrict__ pairbuf,
                                                    uint* __restrict__ aggw) {
    __shared__ float agg[BKT_NODES * IN_CH];       // 64 KB
    const int b = blockIdx.x;
    const int t = threadIdx.x;
    const int nbase = b * BKT_NODES;
    const int nloc = (nbase + BKT_NODES <= N_NODES) ? BKT_NODES : (N_NODES - nbase);

    // init: residual x rows (split-word -> real channel slots)
    for (int lin = t; lin < nloc * 64; lin += 512) {
        const int nl = lin >> 6, w = lin & 63;
        const uint v = xw[(size_t)(nbase + nl) * 64 + w];
        agg[nl * IN_CH + w]      = __uint_as_float(v << 16);
        agg[nl * IN_CH + w + 64] = __uint_as_float(v & 0xffff0000u);
    }
    __syncthreads();

    const int ne = bucketcnt[b];
    const uint* eb = pairbuf + (size_t)b * BCAP;
    const int lane = t & 63;
    const int wv   = t >> 6;

    // 8-deep pipelined edge loop; each wave takes 8-edge chunks strided by 64
    for (int i0 = wv * 8; i0 < ne; i0 += 64) {
        const int c8 = (ne - i0 >= 8) ? 8 : (ne - i0);
        const uint4 pa = *(const uint4*)(eb + i0);      // 32B-aligned broadcast
        const uint4 pb = *(const uint4*)(eb + i0 + 4);
        uint p[8];
        p[0] = pa.x; p[1] = pa.y; p[2] = pa.z; p[3] = pa.w;
        p[4] = pb.x; p[5] = pb.y; p[6] = pb.z; p[7] = pb.w;
        uint v[8];
#pragma unroll
        for (int j = 0; j < 8; ++j)
            if (j < c8) v[j] = xw[(size_t)((p[j] >> 7) & 0xFFFFu) * 64 + lane];
#pragma unroll
        for (int j = 0; j < 8; ++j)
            if (j < c8) {
                const int dl = (int)(p[j] & (BKT_NODES - 1));
                atomicAdd(&agg[dl * IN_CH + lane],      __uint_as_float(v[j] << 16));
                atomicAdd(&agg[dl * IN_CH + lane + 64], __uint_as_float(v[j] & 0xffff0000u));
            }
    }
    __syncthreads();

    // writeback: standard pair layout (word j = ch 2j | ch 2j+1) for the GEMM
    for (int lin = t; lin < nloc * 64; lin += 512) {
        const int nl = lin >> 6, j = lin & 63;
        const float c0 = agg[nl * IN_CH + 2 * j];
        const float c1 = agg[nl * IN_CH + 2 * j + 1];
        aggw[(size_t)(nbase + nl) * 64 + j] = ((uint)f2bf(c1) << 16) | (uint)f2bf(c0);
    }
}

// ---------------------------------------------------------------------------
// out[50000,256] = aggb @ W12 + b2   via bf16 MFMA 16x16x32.
// ---------------------------------------------------------------------------
__global__ __launch_bounds__(512) void mfma_gemm(const ushort* __restrict__ aggb,
                                                 const ushort* __restrict__ w12t,
                                                 const float* __restrict__ b2,
                                                 float* __restrict__ out) {
    __shared__ ushort bt[256 * 128];               // 64 KB
    const int tid = threadIdx.x;

#pragma unroll
    for (int it = 0; it < 8; ++it) {
        const int i = tid + it * 512;              // 0..4095
        const int n = i >> 4, s = i & 15;
        const uint4 v = *(const uint4*)(w12t + (size_t)i * 8);
        *(uint4*)(&bt[(n << 7) + ((s ^ (n & 7)) << 3)]) = v;
    }
    __syncthreads();

    const int lane = tid & 63;
    const int w    = tid >> 6;
    const int rbase = blockIdx.x * 256 + (w >> 1) * 64;
    const int cbase = (w & 1) * 128;
    const int l15 = lane & 15;
    const int oct = lane >> 4;

    f32x4 acc[4][8];
#pragma unroll
    for (int m = 0; m < 4; ++m)
#pragma unroll
        for (int n = 0; n < 8; ++n)
            acc[m][n] = (f32x4){0.f, 0.f, 0.f, 0.f};

#pragma unroll
    for (int kk = 0; kk < 4; ++kk) {               // k = kk*32 + oct*8 + j
        bf16x8 afr[4];
#pragma unroll
        for (int m = 0; m < 4; ++m) {
            int row = rbase + m * 16 + l15;
            row = row < N_NODES ? row : N_NODES - 1;
            afr[m] = *(const bf16x8*)(aggb + (size_t)row * IN_CH + kk * 32 + oct * 8);
        }
#pragma unroll
        for (int n = 0; n < 8; ++n) {
            const int col  = cbase + n * 16 + l15;
            const int slot = (kk * 4 + oct) ^ (col & 7);
            const bf16x8 bfr = *(const bf16x8*)(&bt[(col << 7) + (slot << 3)]);
#pragma unroll
            for (int m = 0; m < 4; ++m)
                acc[m][n] = __builtin_amdgcn_mfma_f32_16x16x32_bf16(
                    afr[m], bfr, acc[m][n], 0, 0, 0);
        }
    }

#pragma unroll
    for (int m = 0; m < 4; ++m) {
        const int row0 = rbase + m * 16 + oct * 4;
#pragma unroll
        for (int n = 0; n < 8; ++n) {
            const int col = cbase + n * 16 + l15;
            const float bias = b2[col];
#pragma unroll
            for (int r = 0; r < 4; ++r) {
                const int row = row0 + r;
                if (row < N_NODES)
                    out[(size_t)row * OUT_CH + col] = acc[m][n][r] + bias;
            }
        }
    }
}

// ---------------------------------------------------------------------------
extern "C" void kernel_launch(void* const* d_in, const int* in_sizes, int n_in,
                              void* d_out, int out_size, void* d_ws, size_t ws_size,
                              hipStream_t stream) {
    const float* x  = (const float*)d_in[0];
    const int*   ei = (const int*)d_in[1];      // [2, N_EDGES] int32
    const float* W1 = (const float*)d_in[2];
    const float* b1 = (const float*)d_in[3];
    const float* W2 = (const float*)d_in[4];
    float* out = (float*)d_out;

    // workspace layout (bytes)
    char* ws = (char*)d_ws;
    uint*   xw        = (uint*)  (ws + 0);               // 12,800,000 (split layout)
    uint*   aggw      = (uint*)  (ws + 12800000);        // 12,800,000 (standard pairs)
    ushort* W12t      = (ushort*)(ws + 25600000);        //     65,536
    float*  b2        = (float*) (ws + 25665536);        //      1,024
    uint*   pairbuf   = (uint*)  (ws + 25666560);        //  6,406,144 (391*4096*4)
    int*    bucketcnt = (int*)   (ws + 32072704);        //      1,564  -> ~32.1 MB

    // 1) collapse MLP -> bf16 W12^T + f32 b2
    build_w12<<<dim3(IN_CH + 1), dim3(256), 0, stream>>>(W1, b1, W2, W12t, b2);

    // 2) x -> bf16 split-words (+ zero bucketcnt)
    cvt_bf16<<<dim3(N_NODES * 64 / 256), dim3(256), 0, stream>>>(x, xw, bucketcnt);

    // 3) partition edges into fixed-capacity dst-buckets
    partition_edges<<<dim3(P1_BLOCKS), dim3(512), 0, stream>>>(ei, bucketcnt, pairbuf);

    // 4) per-bucket LDS accumulate (residual folded) -> aggw bf16
    bucket_accum<<<dim3(NBKT), dim3(512), 0, stream>>>(xw, bucketcnt, pairbuf, aggw);

    // 5) out = aggb @ W12 + b2   (bf16 MFMA)
    mfma_gemm<<<dim3((N_NODES + 255) / 256), dim3(512), 0, stream>>>(
        (const ushort*)aggw, W12t, b2, out);
}

// Round 9
// 112.845 us; speedup vs baseline: 6.7574x; 6.7574x over previous
//
#include <hip/hip_runtime.h>

#define N_NODES 50000
#define N_EDGES 800000
#define IN_CH   128
#define HID_CH  512
#define OUT_CH  256

// 512-node dst-buckets, fixed capacity (mean 8192, +4sigma ~8550, cap 16384)
#define BKT_SHIFT 9
#define BKT_NODES 512
#define NBKT ((N_NODES + BKT_NODES - 1) / BKT_NODES)        // 98
#define BCAP 16384
#define P1_EPT    8
#define P1_EPB    (512 * P1_EPT)                            // 4096 edges/block
#define P1_BLOCKS ((N_EDGES + P1_EPB - 1) / P1_EPB)         // 196

typedef __attribute__((ext_vector_type(8))) short bf16x8;
typedef __attribute__((ext_vector_type(4))) float f32x4;

static __device__ __forceinline__ ushort f2bf(float f) {
    uint u = __float_as_uint(f);
    uint r = u + 0x7fffu + ((u >> 16) & 1u);   // RNE; inputs are finite
    return (ushort)(r >> 16);
}

// ---------------------------------------------------------------------------
// W12t[j][i] = sum_k W1[i][k]*W2[k][j]  (bf16, TRANSPOSED: [256][128])
// b2[j]     = sum_k b1[k]*W2[k][j]     (f32)
// ---------------------------------------------------------------------------
__global__ void build_w12(const float* __restrict__ W1,
                          const float* __restrict__ b1,
                          const float* __restrict__ W2,
                          ushort* __restrict__ W12t,
                          float* __restrict__ b2) {
    const int i = blockIdx.x;        // 0..128 (128 == bias row)
    const int j = threadIdx.x;       // 0..255
    const float* arow = (i < IN_CH) ? (W1 + (size_t)i * HID_CH) : b1;
    float acc = 0.f;
#pragma unroll 8
    for (int k = 0; k < HID_CH; ++k)
        acc = fmaf(arow[k], W2[(size_t)k * OUT_CH + j], acc);
    if (i < IN_CH) W12t[(size_t)j * IN_CH + i] = f2bf(acc);
    else           b2[j] = acc;
}

// ---------------------------------------------------------------------------
// x (f32) -> xb (bf16, standard row-major); also zeroes bucketcnt.
// ---------------------------------------------------------------------------
__global__ void cvt_bf16(const float* __restrict__ x, ushort* __restrict__ xb,
                         int* __restrict__ bucketcnt) {
    const int gid = blockIdx.x * 256 + threadIdx.x;
    if (gid < NBKT) bucketcnt[gid] = 0;
    if (gid >= N_NODES * IN_CH / 4) return;
    const float4 v = *(const float4*)(x + (size_t)gid * 4);
    ushort4 o;
    o.x = f2bf(v.x); o.y = f2bf(v.y); o.z = f2bf(v.z); o.w = f2bf(v.w);
    *(ushort4*)(xb + (size_t)gid * 4) = o;
}

// ---------------------------------------------------------------------------
// Partition edges into 98 fixed-capacity dst-buckets (512 nodes each).
// Packed word: b<<25 | src<<9 | (dst&511). LDS-staged, bucket-contiguous
// coalesced writes; per-bucket base = b*BCAP + atomicAdd(bucketcnt[b]).
// ---------------------------------------------------------------------------
__global__ __launch_bounds__(512) void partition_edges(const int* __restrict__ ei,
                                                       int* __restrict__ bucketcnt,
                                                       uint* __restrict__ pairbuf) {
    __shared__ uint stage[P1_EPB];                 // 16 KB
    __shared__ int cnt[128], off[128], cur[128], base[128];
    const int t = threadIdx.x;
    const int e0 = blockIdx.x * P1_EPB;

    if (t < 128) cnt[t] = 0;
    __syncthreads();

    uint pk[P1_EPT];
    int  bk[P1_EPT];
    bool vl[P1_EPT];
#pragma unroll
    for (int i = 0; i < P1_EPT; ++i) {
        const int e = e0 + i * 512 + t;
        vl[i] = (e < N_EDGES);
        if (vl[i]) {
            const int src = ei[e];
            const int dst = ei[N_EDGES + e];
            const int b = dst >> BKT_SHIFT;
            bk[i] = b;
            pk[i] = ((uint)b << 25) | ((uint)src << 9) | (uint)(dst & (BKT_NODES - 1));
            atomicAdd(&cnt[b], 1);
        }
    }
    __syncthreads();

    // exclusive scan of cnt[0..127] -> off
    if (t < 128) off[t] = cnt[t];
    __syncthreads();
#pragma unroll
    for (int d = 1; d < 128; d <<= 1) {
        int u = 0;
        if (t < 128 && t >= d) u = off[t - d];
        __syncthreads();
        if (t < 128 && t >= d) off[t] += u;
        __syncthreads();
    }
    if (t < 128) {
        off[t] -= cnt[t];                          // exclusive
        cur[t] = off[t];
        if (t < NBKT && cnt[t] > 0)
            base[t] = t * BCAP + atomicAdd(&bucketcnt[t], cnt[t]);
    }
    __syncthreads();

#pragma unroll
    for (int i = 0; i < P1_EPT; ++i)
        if (vl[i]) {
            const int lp = atomicAdd(&cur[bk[i]], 1);
            stage[lp] = pk[i];
        }
    __syncthreads();

    const int TOT = off[127] + cnt[127];
    for (int idx = t; idx < TOT; idx += 512) {
        const uint p = stage[idx];
        const int b = (int)(p >> 25);
        pairbuf[base[b] + (idx - off[b])] = p;
    }
}

// ---------------------------------------------------------------------------
// Per-bucket local counting sort: pairbuf bucket -> bucket-local CSR
// (locrow[b][0..512] node offsets, srcidx[b*BCAP + pos] sources).
// Replaces global hist+scan+add_offsets+fill (5 kernels -> 1).
// ---------------------------------------------------------------------------
__global__ __launch_bounds__(512) void bucket_fill2(const uint* __restrict__ pairbuf,
                                                    const int* __restrict__ bucketcnt,
                                                    int* __restrict__ locrow,
                                                    int* __restrict__ srcidx) {
    __shared__ int cnt[512], off[512], cur[512];
    const int b = blockIdx.x;
    const int t = threadIdx.x;
    const int ne = bucketcnt[b];
    const uint* eb = pairbuf + (size_t)b * BCAP;

    cnt[t] = 0;
    __syncthreads();
    for (int i = t; i < ne; i += 512)
        atomicAdd(&cnt[eb[i] & (BKT_NODES - 1)], 1);
    __syncthreads();

    // exclusive scan of cnt -> off (Hillis-Steele inclusive, then subtract)
    off[t] = cnt[t];
    __syncthreads();
#pragma unroll
    for (int d = 1; d < 512; d <<= 1) {
        const int u = (t >= d) ? off[t - d] : 0;
        __syncthreads();
        off[t] += u;
        __syncthreads();
    }
    off[t] -= cnt[t];
    cur[t] = off[t];
    locrow[b * 513 + t] = off[t];
    if (t == 0) locrow[b * 513 + 512] = ne;
    __syncthreads();

    for (int i = t; i < ne; i += 512) {
        const uint p = eb[i];
        const int ln  = (int)(p & (BKT_NODES - 1));
        const int src = (int)((p >> 9) & 0xFFFFu);
        const int pos = atomicAdd(&cur[ln], 1);
        srcidx[(size_t)b * BCAP + pos] = src;
    }
}

// ---------------------------------------------------------------------------
// Gather (bf16 rows, f32 accumulate): agg[n] = x[n] + sum_{e in in(n)} x[src]
// One wave per node, register accumulation (50K waves). Bucket-local CSR.
// ---------------------------------------------------------------------------
__global__ __launch_bounds__(256) void gather_bf16(const ushort* __restrict__ xb,
                                                   const int* __restrict__ locrow,
                                                   const int* __restrict__ srcidx,
                                                   ushort* __restrict__ aggb) {
    const int node = (int)((blockIdx.x * 256u + threadIdx.x) >> 6);
    const int lane = threadIdx.x & 63;
    if (node >= N_NODES) return;
    const int b  = node >> BKT_SHIFT;
    const int ln = node & (BKT_NODES - 1);
    const uint* xrow = (const uint*)xb;            // 64 uints per node row
    const uint self = xrow[(size_t)node * 64 + lane];
    float ax = __uint_as_float(self << 16);
    float ay = __uint_as_float(self & 0xffff0000u);
    int e = locrow[b * 513 + ln];
    const int end = locrow[b * 513 + ln + 1];
    const int* sb = srcidx + (size_t)b * BCAP;
    for (; e + 8 <= end; e += 8) {
        uint v[8];
#pragma unroll
        for (int i = 0; i < 8; ++i) {
            const int s = sb[e + i];
            v[i] = xrow[(size_t)s * 64 + lane];
        }
#pragma unroll
        for (int i = 0; i < 8; ++i) {
            ax += __uint_as_float(v[i] << 16);
            ay += __uint_as_float(v[i] & 0xffff0000u);
        }
    }
    for (; e < end; ++e) {
        const uint v = xrow[(size_t)sb[e] * 64 + lane];
        ax += __uint_as_float(v << 16); ay += __uint_as_float(v & 0xffff0000u);
    }
    const uint packed = ((uint)f2bf(ay) << 16) | (uint)f2bf(ax);
    ((uint*)aggb)[(size_t)node * 64 + lane] = packed;
}

// ---------------------------------------------------------------------------
// out[50000,256] = aggb @ W12 + b2   via bf16 MFMA 16x16x32.
// ---------------------------------------------------------------------------
__global__ __launch_bounds__(512) void mfma_gemm(const ushort* __restrict__ aggb,
                                                 const ushort* __restrict__ w12t,
                                                 const float* __restrict__ b2,
                                                 float* __restrict__ out) {
    __shared__ ushort bt[256 * 128];               // 64 KB
    const int tid = threadIdx.x;

#pragma unroll
    for (int it = 0; it < 8; ++it) {
        const int i = tid + it * 512;              // 0..4095
        const int n = i >> 4, s = i & 15;
        const uint4 v = *(const uint4*)(w12t + (size_t)i * 8);
        *(uint4*)(&bt[(n << 7) + ((s ^ (n & 7)) << 3)]) = v;
    }
    __syncthreads();

    const int lane = tid & 63;
    const int w    = tid >> 6;
    const int rbase = blockIdx.x * 256 + (w >> 1) * 64;
    const int cbase = (w & 1) * 128;
    const int l15 = lane & 15;
    const int oct = lane >> 4;

    f32x4 acc[4][8];
#pragma unroll
    for (int m = 0; m < 4; ++m)
#pragma unroll
        for (int n = 0; n < 8; ++n)
            acc[m][n] = (f32x4){0.f, 0.f, 0.f, 0.f};

#pragma unroll
    for (int kk = 0; kk < 4; ++kk) {               // k = kk*32 + oct*8 + j
        bf16x8 afr[4];
#pragma unroll
        for (int m = 0; m < 4; ++m) {
            int row = rbase + m * 16 + l15;
            row = row < N_NODES ? row : N_NODES - 1;
            afr[m] = *(const bf16x8*)(aggb + (size_t)row * IN_CH + kk * 32 + oct * 8);
        }
#pragma unroll
        for (int n = 0; n < 8; ++n) {
            const int col  = cbase + n * 16 + l15;
            const int slot = (kk * 4 + oct) ^ (col & 7);
            const bf16x8 bfr = *(const bf16x8*)(&bt[(col << 7) + (slot << 3)]);
#pragma unroll
            for (int m = 0; m < 4; ++m)
                acc[m][n] = __builtin_amdgcn_mfma_f32_16x16x32_bf16(
                    afr[m], bfr, acc[m][n], 0, 0, 0);
        }
    }

#pragma unroll
    for (int m = 0; m < 4; ++m) {
        const int row0 = rbase + m * 16 + oct * 4;
#pragma unroll
        for (int n = 0; n < 8; ++n) {
            const int col = cbase + n * 16 + l15;
            const float bias = b2[col];
#pragma unroll
            for (int r = 0; r < 4; ++r) {
                const int row = row0 + r;
                if (row < N_NODES)
                    out[(size_t)row * OUT_CH + col] = acc[m][n][r] + bias;
            }
        }
    }
}

// ---------------------------------------------------------------------------
extern "C" void kernel_launch(void* const* d_in, const int* in_sizes, int n_in,
                              void* d_out, int out_size, void* d_ws, size_t ws_size,
                              hipStream_t stream) {
    const float* x  = (const float*)d_in[0];
    const int*   ei = (const int*)d_in[1];      // [2, N_EDGES] int32
    const float* W1 = (const float*)d_in[2];
    const float* b1 = (const float*)d_in[3];
    const float* W2 = (const float*)d_in[4];
    float* out = (float*)d_out;

    // workspace layout (bytes)
    char* ws = (char*)d_ws;
    ushort* xb        = (ushort*)(ws + 0);               // 12,800,000
    ushort* aggb      = (ushort*)(ws + 12800000);        // 12,800,000
    uint*   pairbuf   = (uint*)  (ws + 12800000);        //  6,422,528 (aliases aggb;
                                                         //   dead before gather runs)
    ushort* W12t      = (ushort*)(ws + 25600000);        //     65,536
    float*  b2        = (float*) (ws + 25665536);        //      1,024
    int*    srcidx    = (int*)   (ws + 25666560);        //  6,422,528 (98*16384*4)
    int*    locrow    = (int*)   (ws + 32089088);        //    201,096 (98*513*4)
    int*    bucketcnt = (int*)   (ws + 32290184);        //        392  -> ~32.3 MB

    // 1) collapse MLP -> bf16 W12^T + f32 b2
    build_w12<<<dim3(IN_CH + 1), dim3(256), 0, stream>>>(W1, b1, W2, W12t, b2);

    // 2) x -> bf16 (+ zero bucketcnt)
    cvt_bf16<<<dim3((N_NODES * IN_CH / 4 + 255) / 256), dim3(256), 0, stream>>>(
        x, xb, bucketcnt);

    // 3) partition edges into fixed-capacity dst-buckets
    partition_edges<<<dim3(P1_BLOCKS), dim3(512), 0, stream>>>(ei, bucketcnt, pairbuf);

    // 4) per-bucket local counting sort -> bucket-local CSR
    bucket_fill2<<<dim3(NBKT), dim3(512), 0, stream>>>(pairbuf, bucketcnt,
                                                       locrow, srcidx);

    // 5) gather (residual folded): aggb[n] = x[n] + sum x[src]   (bf16)
    gather_bf16<<<dim3(N_NODES * 64 / 256), dim3(256), 0, stream>>>(
        xb, locrow, srcidx, aggb);

    // 6) out = aggb @ W12 + b2   (bf16 MFMA)
    mfma_gemm<<<dim3((N_NODES + 255) / 256), dim3(512), 0, stream>>>(
        aggb, W12t, b2, out);
}

// Round 10
// 99.155 us; speedup vs baseline: 7.6904x; 1.1381x over previous
//
#include <hip/hip_runtime.h>

#define N_NODES 50000
#define N_EDGES 800000
#define IN_CH   128
#define HID_CH  512
#define OUT_CH  256

// 512-node dst-buckets, fixed capacity (mean 8192, +4sigma ~8550, cap 16384)
#define BKT_SHIFT 9
#define BKT_NODES 512
#define NBKT ((N_NODES + BKT_NODES - 1) / BKT_NODES)        // 98
#define BCAP 16384
#define P1_EPT    8
#define P1_EPB    (512 * P1_EPT)                            // 4096 edges/block
#define P1_BLOCKS ((N_EDGES + P1_EPB - 1) / P1_EPB)         // 196
#define CVT_BLOCKS 3125                                     // 1.6M float4 / 512

typedef __attribute__((ext_vector_type(8))) short bf16x8;
typedef __attribute__((ext_vector_type(4))) float f32x4;

static __device__ __forceinline__ ushort f2bf(float f) {
    uint u = __float_as_uint(f);
    uint r = u + 0x7fffu + ((u >> 16) & 1u);   // RNE; inputs are finite
    return (ushort)(r >> 16);
}

// ---------------------------------------------------------------------------
// W12t[j][i] = sum_k W1[i][k]*W2[k][j]  (bf16, TRANSPOSED [256][128])
// b2[j] = sum_k b1[k]*W2[k][j]          (f32)
// 33 blocks x 1024 thr: blocks 0..31 = 4 W1-rows each (LDS-staged), block 32
// = bias row. Threads = 256 j x 4 k-chunks; LDS reduce over chunks.
// Also zeroes bucketcnt (block 0) for the downstream partition.
// ---------------------------------------------------------------------------
__global__ __launch_bounds__(1024) void build_w12(const float* __restrict__ W1,
                                                  const float* __restrict__ b1,
                                                  const float* __restrict__ W2,
                                                  ushort* __restrict__ W12t,
                                                  float* __restrict__ b2,
                                                  int* __restrict__ bucketcnt) {
    __shared__ float a[4][HID_CH];                 // 8 KB
    __shared__ float red[4][4][256];               // 16 KB  [kc][row][j]
    const int t   = threadIdx.x;
    const int j   = t & 255;
    const int kc  = t >> 8;                        // 0..3
    const int blk = blockIdx.x;
    if (blk == 0 && t < NBKT) bucketcnt[t] = 0;

    const bool bias = (blk == 32);
    if (!bias) {
        const int i0 = blk * 4;
        for (int lin = t; lin < 4 * HID_CH; lin += 1024)
            a[lin >> 9][lin & 511] = W1[(size_t)(i0 + (lin >> 9)) * HID_CH + (lin & 511)];
    } else {
        for (int lin = t; lin < HID_CH; lin += 1024) a[0][lin] = b1[lin];
    }
    __syncthreads();

    float acc[4] = {0.f, 0.f, 0.f, 0.f};
    const int k0 = kc * 128;
    if (!bias) {
        for (int k = k0; k < k0 + 128; ++k) {
            const float w = W2[(size_t)k * OUT_CH + j];
#pragma unroll
            for (int r = 0; r < 4; ++r) acc[r] = fmaf(a[r][k], w, acc[r]);
        }
    } else {
        for (int k = k0; k < k0 + 128; ++k)
            acc[0] = fmaf(a[0][k], W2[(size_t)k * OUT_CH + j], acc[0]);
    }
#pragma unroll
    for (int r = 0; r < 4; ++r) red[kc][r][j] = acc[r];
    __syncthreads();
    if (kc == 0) {
#pragma unroll
        for (int r = 0; r < 4; ++r) {
            const float s = red[0][r][j] + red[1][r][j] + red[2][r][j] + red[3][r][j];
            if (!bias) W12t[(size_t)j * IN_CH + blk * 4 + r] = f2bf(s);
            else if (r == 0) b2[j] = s;
        }
    }
}

// ---------------------------------------------------------------------------
// FUSED: blocks 0..3124 convert x->xb (bf16); blocks 3125..3320 partition
// edges into 98 fixed-capacity dst-buckets (independent work, one launch).
// Packed word: b<<25 | src<<9 | (dst&511).
// ---------------------------------------------------------------------------
__global__ __launch_bounds__(512) void cvt_part(const float* __restrict__ x,
                                                ushort* __restrict__ xb,
                                                const int* __restrict__ ei,
                                                int* __restrict__ bucketcnt,
                                                uint* __restrict__ pairbuf) {
    __shared__ uint stage[P1_EPB];                 // 16 KB (partition branch only)
    __shared__ int cnt[128], off[128], cur[128], base[128];
    const int t = threadIdx.x;

    if (blockIdx.x < CVT_BLOCKS) {
        const int gid = blockIdx.x * 512 + t;      // 3125*512 == 1.6M exactly
        const float4 v = *(const float4*)(x + (size_t)gid * 4);
        ushort4 o;
        o.x = f2bf(v.x); o.y = f2bf(v.y); o.z = f2bf(v.z); o.w = f2bf(v.w);
        *(ushort4*)(xb + (size_t)gid * 4) = o;
        return;
    }

    const int e0 = (blockIdx.x - CVT_BLOCKS) * P1_EPB;

    if (t < 128) cnt[t] = 0;
    __syncthreads();

    uint pk[P1_EPT];
    int  bk[P1_EPT];
    bool vl[P1_EPT];
#pragma unroll
    for (int i = 0; i < P1_EPT; ++i) {
        const int e = e0 + i * 512 + t;
        vl[i] = (e < N_EDGES);
        if (vl[i]) {
            const int src = ei[e];
            const int dst = ei[N_EDGES + e];
            const int b = dst >> BKT_SHIFT;
            bk[i] = b;
            pk[i] = ((uint)b << 25) | ((uint)src << 9) | (uint)(dst & (BKT_NODES - 1));
            atomicAdd(&cnt[b], 1);
        }
    }
    __syncthreads();

    // exclusive scan of cnt[0..127] -> off
    if (t < 128) off[t] = cnt[t];
    __syncthreads();
#pragma unroll
    for (int d = 1; d < 128; d <<= 1) {
        int u = 0;
        if (t < 128 && t >= d) u = off[t - d];
        __syncthreads();
        if (t < 128 && t >= d) off[t] += u;
        __syncthreads();
    }
    if (t < 128) {
        off[t] -= cnt[t];                          // exclusive
        cur[t] = off[t];
        if (t < NBKT && cnt[t] > 0)
            base[t] = t * BCAP + atomicAdd(&bucketcnt[t], cnt[t]);
    }
    __syncthreads();

#pragma unroll
    for (int i = 0; i < P1_EPT; ++i)
        if (vl[i]) {
            const int lp = atomicAdd(&cur[bk[i]], 1);
            stage[lp] = pk[i];
        }
    __syncthreads();

    const int TOT = off[127] + cnt[127];
    for (int idx = t; idx < TOT; idx += 512) {
        const uint p = stage[idx];
        const int b = (int)(p >> 25);
        pairbuf[base[b] + (idx - off[b])] = p;
    }
}

// ---------------------------------------------------------------------------
// Per-bucket local counting sort: pairbuf bucket -> bucket-local CSR
// ---------------------------------------------------------------------------
__global__ __launch_bounds__(512) void bucket_fill2(const uint* __restrict__ pairbuf,
                                                    const int* __restrict__ bucketcnt,
                                                    int* __restrict__ locrow,
                                                    int* __restrict__ srcidx) {
    __shared__ int cnt[512], off[512], cur[512];
    const int b = blockIdx.x;
    const int t = threadIdx.x;
    const int ne = bucketcnt[b];
    const uint* eb = pairbuf + (size_t)b * BCAP;

    cnt[t] = 0;
    __syncthreads();
    for (int i = t; i < ne; i += 512)
        atomicAdd(&cnt[eb[i] & (BKT_NODES - 1)], 1);
    __syncthreads();

    off[t] = cnt[t];
    __syncthreads();
#pragma unroll
    for (int d = 1; d < 512; d <<= 1) {
        const int u = (t >= d) ? off[t - d] : 0;
        __syncthreads();
        off[t] += u;
        __syncthreads();
    }
    off[t] -= cnt[t];
    cur[t] = off[t];
    locrow[b * 513 + t] = off[t];
    if (t == 0) locrow[b * 513 + 512] = ne;
    __syncthreads();

    for (int i = t; i < ne; i += 512) {
        const uint p = eb[i];
        const int ln  = (int)(p & (BKT_NODES - 1));
        const int src = (int)((p >> 9) & 0xFFFFu);
        const int pos = atomicAdd(&cur[ln], 1);
        srcidx[(size_t)b * BCAP + pos] = src;
    }
}

// ---------------------------------------------------------------------------
// Gather (bf16 rows, f32 accumulate): agg[n] = x[n] + sum_{e in in(n)} x[src]
// One wave per node, register accumulation (50K waves). Bucket-local CSR.
// ---------------------------------------------------------------------------
__global__ __launch_bounds__(256) void gather_bf16(const ushort* __restrict__ xb,
                                                   const int* __restrict__ locrow,
                                                   const int* __restrict__ srcidx,
                                                   ushort* __restrict__ aggb) {
    const int node = (int)((blockIdx.x * 256u + threadIdx.x) >> 6);
    const int lane = threadIdx.x & 63;
    if (node >= N_NODES) return;
    const int b  = node >> BKT_SHIFT;
    const int ln = node & (BKT_NODES - 1);
    const uint* xrow = (const uint*)xb;            // 64 uints per node row
    const uint self = xrow[(size_t)node * 64 + lane];
    float ax = __uint_as_float(self << 16);
    float ay = __uint_as_float(self & 0xffff0000u);
    int e = locrow[b * 513 + ln];
    const int end = locrow[b * 513 + ln + 1];
    const int* sb = srcidx + (size_t)b * BCAP;
    for (; e + 8 <= end; e += 8) {
        uint v[8];
#pragma unroll
        for (int i = 0; i < 8; ++i) {
            const int s = sb[e + i];
            v[i] = xrow[(size_t)s * 64 + lane];
        }
#pragma unroll
        for (int i = 0; i < 8; ++i) {
            ax += __uint_as_float(v[i] << 16);
            ay += __uint_as_float(v[i] & 0xffff0000u);
        }
    }
    for (; e < end; ++e) {
        const uint v = xrow[(size_t)sb[e] * 64 + lane];
        ax += __uint_as_float(v << 16); ay += __uint_as_float(v & 0xffff0000u);
    }
    const uint packed = ((uint)f2bf(ay) << 16) | (uint)f2bf(ax);
    ((uint*)aggb)[(size_t)node * 64 + lane] = packed;
}

// ---------------------------------------------------------------------------
// out[50000,256] = aggb @ W12 + b2   via bf16 MFMA 16x16x32.
// Nontemporal stores for `out` (51.2 MB, never re-read).
// ---------------------------------------------------------------------------
__global__ __launch_bounds__(512) void mfma_gemm(const ushort* __restrict__ aggb,
                                                 const ushort* __restrict__ w12t,
                                                 const float* __restrict__ b2,
                                                 float* __restrict__ out) {
    __shared__ ushort bt[256 * 128];               // 64 KB
    const int tid = threadIdx.x;

#pragma unroll
    for (int it = 0; it < 8; ++it) {
        const int i = tid + it * 512;              // 0..4095
        const int n = i >> 4, s = i & 15;
        const uint4 v = *(const uint4*)(w12t + (size_t)i * 8);
        *(uint4*)(&bt[(n << 7) + ((s ^ (n & 7)) << 3)]) = v;
    }
    __syncthreads();

    const int lane = tid & 63;
    const int w    = tid >> 6;
    const int rbase = blockIdx.x * 256 + (w >> 1) * 64;
    const int cbase = (w & 1) * 128;
    const int l15 = lane & 15;
    const int oct = lane >> 4;

    f32x4 acc[4][8];
#pragma unroll
    for (int m = 0; m < 4; ++m)
#pragma unroll
        for (int n = 0; n < 8; ++n)
            acc[m][n] = (f32x4){0.f, 0.f, 0.f, 0.f};

#pragma unroll
    for (int kk = 0; kk < 4; ++kk) {               // k = kk*32 + oct*8 + j
        bf16x8 afr[4];
#pragma unroll
        for (int m = 0; m < 4; ++m) {
            int row = rbase + m * 16 + l15;
            row = row < N_NODES ? row : N_NODES - 1;
            afr[m] = *(const bf16x8*)(aggb + (size_t)row * IN_CH + kk * 32 + oct * 8);
        }
#pragma unroll
        for (int n = 0; n < 8; ++n) {
            const int col  = cbase + n * 16 + l15;
            const int slot = (kk * 4 + oct) ^ (col & 7);
            const bf16x8 bfr = *(const bf16x8*)(&bt[(col << 7) + (slot << 3)]);
#pragma unroll
            for (int m = 0; m < 4; ++m)
                acc[m][n] = __builtin_amdgcn_mfma_f32_16x16x32_bf16(
                    afr[m], bfr, acc[m][n], 0, 0, 0);
        }
    }

#pragma unroll
    for (int m = 0; m < 4; ++m) {
        const int row0 = rbase + m * 16 + oct * 4;
#pragma unroll
        for (int n = 0; n < 8; ++n) {
            const int col = cbase + n * 16 + l15;
            const float bias = b2[col];
#pragma unroll
            for (int r = 0; r < 4; ++r) {
                const int row = row0 + r;
                if (row < N_NODES)
                    __builtin_nontemporal_store(acc[m][n][r] + bias,
                                                &out[(size_t)row * OUT_CH + col]);
            }
        }
    }
}

// ---------------------------------------------------------------------------
extern "C" void kernel_launch(void* const* d_in, const int* in_sizes, int n_in,
                              void* d_out, int out_size, void* d_ws, size_t ws_size,
                              hipStream_t stream) {
    const float* x  = (const float*)d_in[0];
    const int*   ei = (const int*)d_in[1];      // [2, N_EDGES] int32
    const float* W1 = (const float*)d_in[2];
    const float* b1 = (const float*)d_in[3];
    const float* W2 = (const float*)d_in[4];
    float* out = (float*)d_out;

    // workspace layout (bytes)
    char* ws = (char*)d_ws;
    ushort* xb        = (ushort*)(ws + 0);               // 12,800,000
    ushort* aggb      = (ushort*)(ws + 12800000);        // 12,800,000
    uint*   pairbuf   = (uint*)  (ws + 12800000);        //  6,422,528 (aliases aggb;
                                                         //   dead before gather runs)
    ushort* W12t      = (ushort*)(ws + 25600000);        //     65,536
    float*  b2        = (float*) (ws + 25665536);        //      1,024
    int*    srcidx    = (int*)   (ws + 25666560);        //  6,422,528 (98*16384*4)
    int*    locrow    = (int*)   (ws + 32089088);        //    201,096 (98*513*4)
    int*    bucketcnt = (int*)   (ws + 32290184);        //        392  -> ~32.3 MB

    // 1) collapse MLP -> bf16 W12^T + f32 b2 (+ zero bucketcnt)
    build_w12<<<dim3(33), dim3(1024), 0, stream>>>(W1, b1, W2, W12t, b2, bucketcnt);

    // 2) FUSED: x -> bf16 || partition edges into dst-buckets
    cvt_part<<<dim3(CVT_BLOCKS + P1_BLOCKS), dim3(512), 0, stream>>>(
        x, xb, ei, bucketcnt, pairbuf);

    // 3) per-bucket local counting sort -> bucket-local CSR
    bucket_fill2<<<dim3(NBKT), dim3(512), 0, stream>>>(pairbuf, bucketcnt,
                                                       locrow, srcidx);

    // 4) gather (residual folded): aggb[n] = x[n] + sum x[src]   (bf16)
    gather_bf16<<<dim3(N_NODES * 64 / 256), dim3(256), 0, stream>>>(
        xb, locrow, srcidx, aggb);

    // 5) out = aggb @ W12 + b2   (bf16 MFMA)
    mfma_gemm<<<dim3((N_NODES + 255) / 256), dim3(512), 0, stream>>>(
        aggb, W12t, b2, out);
}

// Round 11
// 93.572 us; speedup vs baseline: 8.1492x; 1.0597x over previous
//
#include <hip/hip_runtime.h>

#define N_NODES 50000
#define N_EDGES 800000
#define IN_CH   128
#define HID_CH  512
#define OUT_CH  256

// 128-node dst-buckets, fixed capacity (mean 2048, sigma~45, cap 4096)
#define BKT_SHIFT 7
#define BKT_NODES 128
#define NBKT ((N_NODES + BKT_NODES - 1) / BKT_NODES)        // 391
#define BCAP 4096
#define P1_EPT    8
#define P1_EPB    (512 * P1_EPT)                            // 4096 edges/block
#define P1_BLOCKS ((N_EDGES + P1_EPB - 1) / P1_EPB)         // 196
#define CVT_BLOCKS 3125                                     // 1.6M float4 / 512

typedef __attribute__((ext_vector_type(8))) short bf16x8;
typedef __attribute__((ext_vector_type(4))) float f32x4;

static __device__ __forceinline__ ushort f2bf(float f) {
    uint u = __float_as_uint(f);
    uint r = u + 0x7fffu + ((u >> 16) & 1u);   // RNE; inputs are finite
    return (ushort)(r >> 16);
}

// ---------------------------------------------------------------------------
// W12t[j][i] = sum_k W1[i][k]*W2[k][j]  (bf16, TRANSPOSED [256][128])
// b2[j] = sum_k b1[k]*W2[k][j]          (f32)
// 33 blocks x 1024 thr; block 0 also zeroes bucketcnt.
// ---------------------------------------------------------------------------
__global__ __launch_bounds__(1024) void build_w12(const float* __restrict__ W1,
                                                  const float* __restrict__ b1,
                                                  const float* __restrict__ W2,
                                                  ushort* __restrict__ W12t,
                                                  float* __restrict__ b2,
                                                  int* __restrict__ bucketcnt) {
    __shared__ float a[4][HID_CH];                 // 8 KB
    __shared__ float red[4][4][256];               // 16 KB  [kc][row][j]
    const int t   = threadIdx.x;
    const int j   = t & 255;
    const int kc  = t >> 8;                        // 0..3
    const int blk = blockIdx.x;
    if (blk == 0 && t < NBKT) bucketcnt[t] = 0;

    const bool bias = (blk == 32);
    if (!bias) {
        const int i0 = blk * 4;
        for (int lin = t; lin < 4 * HID_CH; lin += 1024)
            a[lin >> 9][lin & 511] = W1[(size_t)(i0 + (lin >> 9)) * HID_CH + (lin & 511)];
    } else {
        for (int lin = t; lin < HID_CH; lin += 1024) a[0][lin] = b1[lin];
    }
    __syncthreads();

    float acc[4] = {0.f, 0.f, 0.f, 0.f};
    const int k0 = kc * 128;
    if (!bias) {
        for (int k = k0; k < k0 + 128; ++k) {
            const float w = W2[(size_t)k * OUT_CH + j];
#pragma unroll
            for (int r = 0; r < 4; ++r) acc[r] = fmaf(a[r][k], w, acc[r]);
        }
    } else {
        for (int k = k0; k < k0 + 128; ++k)
            acc[0] = fmaf(a[0][k], W2[(size_t)k * OUT_CH + j], acc[0]);
    }
#pragma unroll
    for (int r = 0; r < 4; ++r) red[kc][r][j] = acc[r];
    __syncthreads();
    if (kc == 0) {
#pragma unroll
        for (int r = 0; r < 4; ++r) {
            const float s = red[0][r][j] + red[1][r][j] + red[2][r][j] + red[3][r][j];
            if (!bias) W12t[(size_t)j * IN_CH + blk * 4 + r] = f2bf(s);
            else if (r == 0) b2[j] = s;
        }
    }
}

// ---------------------------------------------------------------------------
// FUSED: blocks 0..3124 convert x->xb (bf16); blocks 3125..3320 partition
// edges into 391 fixed-capacity dst-buckets (128 nodes each).
// Packed word: b<<23 | src<<7 | (dst&127).
// ---------------------------------------------------------------------------
__global__ __launch_bounds__(512) void cvt_part(const float* __restrict__ x,
                                                ushort* __restrict__ xb,
                                                const int* __restrict__ ei,
                                                int* __restrict__ bucketcnt,
                                                uint* __restrict__ pairbuf) {
    __shared__ uint stage[P1_EPB];                 // 16 KB (partition branch only)
    __shared__ int cnt[512], off[512], cur[512], base[512];
    const int t = threadIdx.x;

    if (blockIdx.x < CVT_BLOCKS) {
        const int gid = blockIdx.x * 512 + t;      // 3125*512 == 1.6M exactly
        const float4 v = *(const float4*)(x + (size_t)gid * 4);
        ushort4 o;
        o.x = f2bf(v.x); o.y = f2bf(v.y); o.z = f2bf(v.z); o.w = f2bf(v.w);
        *(ushort4*)(xb + (size_t)gid * 4) = o;
        return;
    }

    const int e0 = (blockIdx.x - CVT_BLOCKS) * P1_EPB;

    cnt[t] = 0;
    __syncthreads();

    uint pk[P1_EPT];
    int  bk[P1_EPT];
    bool vl[P1_EPT];
#pragma unroll
    for (int i = 0; i < P1_EPT; ++i) {
        const int e = e0 + i * 512 + t;
        vl[i] = (e < N_EDGES);
        if (vl[i]) {
            const int src = ei[e];
            const int dst = ei[N_EDGES + e];
            const int b = dst >> BKT_SHIFT;
            bk[i] = b;
            pk[i] = ((uint)b << 23) | ((uint)src << 7) | (uint)(dst & (BKT_NODES - 1));
            atomicAdd(&cnt[b], 1);
        }
    }
    __syncthreads();

    // exclusive scan of cnt[0..511] -> off
    off[t] = cnt[t];
    __syncthreads();
#pragma unroll
    for (int d = 1; d < 512; d <<= 1) {
        const int u = (t >= d) ? off[t - d] : 0;
        __syncthreads();
        off[t] += u;
        __syncthreads();
    }
    off[t] -= cnt[t];                              // exclusive
    cur[t] = off[t];
    if (t < NBKT && cnt[t] > 0)
        base[t] = t * BCAP + atomicAdd(&bucketcnt[t], cnt[t]);
    __syncthreads();

#pragma unroll
    for (int i = 0; i < P1_EPT; ++i)
        if (vl[i]) {
            const int lp = atomicAdd(&cur[bk[i]], 1);
            stage[lp] = pk[i];
        }
    __syncthreads();

    const int TOT = off[511] + cnt[511];
    for (int idx = t; idx < TOT; idx += 512) {
        const uint p = stage[idx];
        const int b = (int)(p >> 23);
        pairbuf[base[b] + (idx - off[b])] = p;
    }
}

// ---------------------------------------------------------------------------
// Per-bucket local counting sort: pairbuf bucket -> bucket-local CSR.
// 391 blocks x 256 threads (good CU fill), 128-wide scan.
// ---------------------------------------------------------------------------
__global__ __launch_bounds__(256) void bucket_fill2(const uint* __restrict__ pairbuf,
                                                    const int* __restrict__ bucketcnt,
                                                    int* __restrict__ locrow,
                                                    int* __restrict__ srcidx) {
    __shared__ int cnt[128], off[128], cur[128];
    const int b = blockIdx.x;
    const int t = threadIdx.x;
    const int ne = bucketcnt[b];
    const uint* eb = pairbuf + (size_t)b * BCAP;

    if (t < 128) cnt[t] = 0;
    __syncthreads();
    for (int i = t; i < ne; i += 256)
        atomicAdd(&cnt[eb[i] & (BKT_NODES - 1)], 1);
    __syncthreads();

    if (t < 128) off[t] = cnt[t];
    __syncthreads();
#pragma unroll
    for (int d = 1; d < 128; d <<= 1) {
        int u = 0;
        if (t < 128 && t >= d) u = off[t - d];
        __syncthreads();
        if (t < 128 && t >= d) off[t] += u;
        __syncthreads();
    }
    if (t < 128) {
        off[t] -= cnt[t];
        cur[t] = off[t];
        locrow[b * (BKT_NODES + 1) + t] = off[t];
        if (t == 0) locrow[b * (BKT_NODES + 1) + BKT_NODES] = ne;
    }
    __syncthreads();

    for (int i = t; i < ne; i += 256) {
        const uint p = eb[i];
        const int ln  = (int)(p & (BKT_NODES - 1));
        const int src = (int)((p >> 7) & 0xFFFFu);
        const int pos = atomicAdd(&cur[ln], 1);
        srcidx[(size_t)b * BCAP + pos] = src;
    }
}

// ---------------------------------------------------------------------------
// Gather (bf16 rows, f32 accumulate): agg[n] = x[n] + sum_{e in in(n)} x[src]
// One wave per node, register accumulation (50K waves). Bucket-local CSR.
// ---------------------------------------------------------------------------
__global__ __launch_bounds__(256) void gather_bf16(const ushort* __restrict__ xb,
                                                   const int* __restrict__ locrow,
                                                   const int* __restrict__ srcidx,
                                                   ushort* __restrict__ aggb) {
    const int node = (int)((blockIdx.x * 256u + threadIdx.x) >> 6);
    const int lane = threadIdx.x & 63;
    if (node >= N_NODES) return;
    const int b  = node >> BKT_SHIFT;
    const int ln = node & (BKT_NODES - 1);
    const uint* xrow = (const uint*)xb;            // 64 uints per node row
    const uint self = xrow[(size_t)node * 64 + lane];
    float ax = __uint_as_float(self << 16);
    float ay = __uint_as_float(self & 0xffff0000u);
    int e = locrow[b * (BKT_NODES + 1) + ln];
    const int end = locrow[b * (BKT_NODES + 1) + ln + 1];
    const int* sb = srcidx + (size_t)b * BCAP;
    for (; e + 8 <= end; e += 8) {
        uint v[8];
#pragma unroll
        for (int i = 0; i < 8; ++i) {
            const int s = sb[e + i];
            v[i] = xrow[(size_t)s * 64 + lane];
        }
#pragma unroll
        for (int i = 0; i < 8; ++i) {
            ax += __uint_as_float(v[i] << 16);
            ay += __uint_as_float(v[i] & 0xffff0000u);
        }
    }
    for (; e < end; ++e) {
        const uint v = xrow[(size_t)sb[e] * 64 + lane];
        ax += __uint_as_float(v << 16); ay += __uint_as_float(v & 0xffff0000u);
    }
    const uint packed = ((uint)f2bf(ay) << 16) | (uint)f2bf(ax);
    ((uint*)aggb)[(size_t)node * 64 + lane] = packed;
}

// ---------------------------------------------------------------------------
// out[50000,256] = aggb @ W12 + b2 via bf16 MFMA 16x16x32.
// BM=128 -> 391 blocks (full CU coverage). 8 waves: (w>>1) = 32-row quarter,
// (w&1) = 128-col half. Nontemporal stores (out never re-read).
// ---------------------------------------------------------------------------
__global__ __launch_bounds__(512) void mfma_gemm(const ushort* __restrict__ aggb,
                                                 const ushort* __restrict__ w12t,
                                                 const float* __restrict__ b2,
                                                 float* __restrict__ out) {
    __shared__ ushort bt[256 * 128];               // 64 KB
    const int tid = threadIdx.x;

#pragma unroll
    for (int it = 0; it < 8; ++it) {
        const int i = tid + it * 512;              // 0..4095
        const int n = i >> 4, s = i & 15;
        const uint4 v = *(const uint4*)(w12t + (size_t)i * 8);
        *(uint4*)(&bt[(n << 7) + ((s ^ (n & 7)) << 3)]) = v;
    }
    __syncthreads();

    const int lane = tid & 63;
    const int w    = tid >> 6;
    const int rbase = blockIdx.x * 128 + (w >> 1) * 32;
    const int cbase = (w & 1) * 128;
    const int l15 = lane & 15;
    const int oct = lane >> 4;

    f32x4 acc[2][8];
#pragma unroll
    for (int m = 0; m < 2; ++m)
#pragma unroll
        for (int n = 0; n < 8; ++n)
            acc[m][n] = (f32x4){0.f, 0.f, 0.f, 0.f};

#pragma unroll
    for (int kk = 0; kk < 4; ++kk) {               // k = kk*32 + oct*8 + j
        bf16x8 afr[2];
#pragma unroll
        for (int m = 0; m < 2; ++m) {
            int row = rbase + m * 16 + l15;
            row = row < N_NODES ? row : N_NODES - 1;
            afr[m] = *(const bf16x8*)(aggb + (size_t)row * IN_CH + kk * 32 + oct * 8);
        }
#pragma unroll
        for (int n = 0; n < 8; ++n) {
            const int col  = cbase + n * 16 + l15;
            const int slot = (kk * 4 + oct) ^ (col & 7);
            const bf16x8 bfr = *(const bf16x8*)(&bt[(col << 7) + (slot << 3)]);
#pragma unroll
            for (int m = 0; m < 2; ++m)
                acc[m][n] = __builtin_amdgcn_mfma_f32_16x16x32_bf16(
                    afr[m], bfr, acc[m][n], 0, 0, 0);
        }
    }

#pragma unroll
    for (int m = 0; m < 2; ++m) {
        const int row0 = rbase + m * 16 + oct * 4;
#pragma unroll
        for (int n = 0; n < 8; ++n) {
            const int col = cbase + n * 16 + l15;
            const float bias = b2[col];
#pragma unroll
            for (int r = 0; r < 4; ++r) {
                const int row = row0 + r;
                if (row < N_NODES)
                    __builtin_nontemporal_store(acc[m][n][r] + bias,
                                                &out[(size_t)row * OUT_CH + col]);
            }
        }
    }
}

// ---------------------------------------------------------------------------
extern "C" void kernel_launch(void* const* d_in, const int* in_sizes, int n_in,
                              void* d_out, int out_size, void* d_ws, size_t ws_size,
                              hipStream_t stream) {
    const float* x  = (const float*)d_in[0];
    const int*   ei = (const int*)d_in[1];      // [2, N_EDGES] int32
    const float* W1 = (const float*)d_in[2];
    const float* b1 = (const float*)d_in[3];
    const float* W2 = (const float*)d_in[4];
    float* out = (float*)d_out;

    // workspace layout (bytes)
    char* ws = (char*)d_ws;
    ushort* xb        = (ushort*)(ws + 0);               // 12,800,000
    ushort* aggb      = (ushort*)(ws + 12800000);        // 12,800,000
    uint*   pairbuf   = (uint*)  (ws + 12800000);        //  6,406,144 (aliases aggb;
                                                         //   dead before gather runs)
    ushort* W12t      = (ushort*)(ws + 25600000);        //     65,536
    float*  b2        = (float*) (ws + 25665536);        //      1,024
    int*    srcidx    = (int*)   (ws + 25666560);        //  6,406,144 (391*4096*4)
    int*    locrow    = (int*)   (ws + 32072704);        //    201,756 (391*129*4)
    int*    bucketcnt = (int*)   (ws + 32274460);        //      1,564  -> ~32.3 MB

    // 1) collapse MLP -> bf16 W12^T + f32 b2 (+ zero bucketcnt)
    build_w12<<<dim3(33), dim3(1024), 0, stream>>>(W1, b1, W2, W12t, b2, bucketcnt);

    // 2) FUSED: x -> bf16 || partition edges into dst-buckets
    cvt_part<<<dim3(CVT_BLOCKS + P1_BLOCKS), dim3(512), 0, stream>>>(
        x, xb, ei, bucketcnt, pairbuf);

    // 3) per-bucket local counting sort -> bucket-local CSR
    bucket_fill2<<<dim3(NBKT), dim3(256), 0, stream>>>(pairbuf, bucketcnt,
                                                       locrow, srcidx);

    // 4) gather (residual folded): aggb[n] = x[n] + sum x[src]   (bf16)
    gather_bf16<<<dim3(N_NODES * 64 / 256), dim3(256), 0, stream>>>(
        xb, locrow, srcidx, aggb);

    // 5) out = aggb @ W12 + b2   (bf16 MFMA)
    mfma_gemm<<<dim3((N_NODES + 127) / 128), dim3(512), 0, stream>>>(
        aggb, W12t, b2, out);
}